// Round 14
// baseline (199.530 us; speedup 1.0000x reference)
//
#include <hip/hip_runtime.h>
#include <stdint.h>

// CausalSelfAttention fused pipeline, MI355X gfx950.
// B=4, T=2048, C=1024, NH=16, HS=64.
// v13: GEMMs: single-barrier 2-phase glds double-buffer (T3 minimum recipe).
//      Prologue kernels (cvt, wattn_t, wproj_t, bias) merged into k_prep.
//      Attention: unchanged from v12 (proven, ~63 us).

typedef __attribute__((ext_vector_type(8))) _Float16 f16x8;
typedef __attribute__((ext_vector_type(4))) _Float16 f16x4;
typedef __attribute__((ext_vector_type(2))) _Float16 h2;
typedef __attribute__((ext_vector_type(2))) __fp16   fp16x2_t;
typedef __attribute__((ext_vector_type(4))) float    f32x4;

#define NT_   8192    // B*T
#define NC_   1024
#define N3C_  3072

__device__ __forceinline__ uint32_t pkrtz(float a, float b){
  union { fp16x2_t h; uint32_t u; } cv;
  cv.h = __builtin_amdgcn_cvt_pkrtz(a, b);
  return cv.u;
}
__device__ __forceinline__ void glds16(const _Float16* g, _Float16* l){
  __builtin_amdgcn_global_load_lds((const __attribute__((address_space(1))) void*)g,
                                   (__attribute__((address_space(3))) void*)l, 16, 0, 0);
}

// ---------------------------------------------------------------- prologue
// bid [0,2048): x f32 -> f16 (grid-stride).  [2048,2432): wattn transpose
// (2 units of 128 thr).  [2432,2560): wproj transpose.  [2560,2572): bias.
__global__ __launch_bounds__(256) void k_prep(
    const float* __restrict__ x, _Float16* __restrict__ xb,
    const float* __restrict__ wa, _Float16* __restrict__ wT,
    const float* __restrict__ wp, _Float16* __restrict__ wpT,
    const float* __restrict__ ba, float* __restrict__ bp)
{
  int bid = blockIdx.x, tid = threadIdx.x;
  if (bid < 2048){
    int idx = bid*256 + tid, stride = 2048*256;
    int n4 = (NT_*NC_)/4;
    for (int i = idx; i < n4; i += stride){
      float4 v = ((const float4*)x)[i];
      f16x4 o;
      o[0] = (_Float16)v.x; o[1] = (_Float16)v.y;
      o[2] = (_Float16)v.z; o[3] = (_Float16)v.w;
      ((f16x4*)xb)[i] = o;
    }
    return;
  }
  if (bid < 2432){
    // wT'[m'][c] = wa[c][colmap(m')], m' = part*1024 + h*64 + d
    int W = (bid - 2048)*2 + (tid >> 7);     // 0..767
    int t = tid & 127;
    int m0 = (W / 32)*128, c0 = (W % 32)*32;
    int mcol = m0 + t;
    int part = mcol >> 10, rr = mcol & 1023;
    int mp = part*1024 + (rr & 15)*64 + (rr >> 4);
    alignas(16) _Float16 buf[32];
    #pragma unroll
    for (int cc = 0; cc < 32; cc++)
      buf[cc] = (_Float16)wa[(size_t)(c0+cc)*N3C_ + mcol];
    uint4* dst = (uint4*)(wT + (size_t)mp*NC_ + c0);
    const uint4* sb = (const uint4*)buf;
    dst[0]=sb[0]; dst[1]=sb[1]; dst[2]=sb[2]; dst[3]=sb[3];
    return;
  }
  if (bid < 2560){
    // wpT'[o][c'] = wp[(c'&63)*16 + (c'>>6)][o]
    int W = (bid - 2432)*2 + (tid >> 7);     // 0..255
    int t = tid & 127;
    int o0 = (W / 32)*128, cp0 = (W % 32)*32;
    int o = o0 + t;
    alignas(16) _Float16 buf[32];
    #pragma unroll
    for (int i = 0; i < 32; i++){
      int cp = cp0 + i;
      int row = (cp & 63)*16 + (cp >> 6);
      buf[i] = (_Float16)wp[(size_t)row*NC_ + o];
    }
    uint4* dst = (uint4*)(wpT + (size_t)o*NC_ + cp0);
    const uint4* sb = (const uint4*)buf;
    dst[0]=sb[0]; dst[1]=sb[1]; dst[2]=sb[2]; dst[3]=sb[3];
    return;
  }
  int i = (bid - 2560)*256 + tid;            // 0..3071
  int part = i >> 10, rr = i & 1023, h = rr >> 6, d = rr & 63;
  bp[i] = ba[part*1024 + d*16 + h];
}

// ---------------------------------------------------------------- GEMM
// C[m][n] = sum_k A[m][k]*BT[n][k] + bias[n].  128x128 tile, BK=32, 4 waves.
// 2-phase glds double-buffer: issue next tile into buf^1, compute buf,
// then vmcnt(0) + one raw s_barrier per iteration.
// OUT_HALF=1 (QKV): columns >=2048 (V-part) written in VT layout.
template<int OUT_HALF>
__global__ __launch_bounds__(256) void k_gemm(
    const _Float16* __restrict__ A, const _Float16* __restrict__ BT,
    const float* __restrict__ bias, void* __restrict__ outp,
    _Float16* __restrict__ VTout,
    int M, int N, int K)
{
  __shared__ _Float16 As[2][128][32];
  __shared__ _Float16 Bs[2][128][32];
  int tid = threadIdx.x;
  int wave = tid >> 6, lane = tid & 63;
  int wr = wave >> 1, wc = wave & 1;
  int g = lane >> 4, l15 = lane & 15;
  f32x4 acc[4][4] = {};
  // staging: thread covers rows r0, r0+64, halfs [cs,cs+8).
  // LDS byte offset = wave*1024 + lane*16 (wave-uniform base + lane*16: OK).
  int r0 = tid >> 2, cs = (tid & 3)*8;
  const _Float16* a0 = A  + ((size_t)blockIdx.y*128 + r0)*K + cs;
  const _Float16* b0 = BT + ((size_t)blockIdx.x*128 + r0)*K + cs;
  size_t step64 = (size_t)64*K;
  auto stage = [&](int kt, int buf){
    glds16(a0 + kt,          &As[buf][r0][cs]);
    glds16(a0 + kt + step64, &As[buf][r0 + 64][cs]);
    glds16(b0 + kt,          &Bs[buf][r0][cs]);
    glds16(b0 + kt + step64, &Bs[buf][r0 + 64][cs]);
  };
  stage(0, 0);
  asm volatile("s_waitcnt vmcnt(0)" ::: "memory");
  __builtin_amdgcn_s_barrier();
  int cur = 0;
  for (int kt = 0; kt < K; kt += 32){
    if (kt + 32 < K) stage(kt + 32, cur ^ 1);
    f16x8 af[4], bf[4];
    #pragma unroll
    for (int mi = 0; mi < 4; mi++) af[mi] = *(const f16x8*)&As[cur][wr*64 + mi*16 + l15][g*8];
    #pragma unroll
    for (int ni = 0; ni < 4; ni++) bf[ni] = *(const f16x8*)&Bs[cur][wc*64 + ni*16 + l15][g*8];
    #pragma unroll
    for (int mi = 0; mi < 4; mi++)
      #pragma unroll
      for (int ni = 0; ni < 4; ni++)
        acc[mi][ni] = __builtin_amdgcn_mfma_f32_16x16x32_f16(af[mi], bf[ni], acc[mi][ni], 0, 0, 0);
    asm volatile("s_waitcnt vmcnt(0)" ::: "memory");
    __builtin_amdgcn_s_barrier();
    cur ^= 1;
  }
  int rowBase = blockIdx.y*128 + wr*64;
  int colBase = blockIdx.x*128 + wc*64;
  if (OUT_HALF && colBase >= 2048){
    // V-part: write VT[bh][d][t], bh = b*16+h, from col = 2048 + h*64 + d
    int b = rowBase >> 11;
    int t0 = (rowBase & 2047);
    #pragma unroll
    for (int mi = 0; mi < 4; mi++){
      #pragma unroll
      for (int ni = 0; ni < 4; ni++){
        int col = colBase + ni*16 + l15;
        int cc = col - 2048;
        int h = cc >> 6, d = cc & 63;
        float bv = bias[col];
        _Float16* dst = VTout + (((size_t)(b*16 + h)*64 + d)*2048) + t0 + mi*16 + g*4;
        f16x4 o;
        #pragma unroll
        for (int r = 0; r < 4; r++) o[r] = (_Float16)(acc[mi][ni][r] + bv);
        *(f16x4*)dst = o;
      }
    }
    return;
  }
  #pragma unroll
  for (int mi = 0; mi < 4; mi++){
    #pragma unroll
    for (int ni = 0; ni < 4; ni++){
      int col = colBase + ni*16 + l15;
      float bv = bias[col];
      #pragma unroll
      for (int r = 0; r < 4; r++){
        int row = rowBase + mi*16 + g*4 + r;
        float v = acc[mi][ni][r] + bv;
        if (OUT_HALF) ((_Float16*)outp)[(size_t)row*N + col] = (_Float16)v;
        else          ((float*)outp)[(size_t)row*N + col] = v;
      }
    }
  }
}

// ---------------------------------------------------------------- attention
// 2-tile balanced flash attention, swapped-operand fixed-offset softmax.
// P = exp2(s' - 12); ratio cancels offset.  No cross-lane in the loop.
// Grid: 1D 1024; bh = bid&63 (XCD-local), j = bid>>6 in 0..15;
// q-tiles {j, 31-j}: uniform 33 processes/block, 4 blocks/CU (160KiB LDS).
__global__ __launch_bounds__(256) void k_attn(
    const _Float16* __restrict__ qkv, const _Float16* __restrict__ VTb,
    _Float16* __restrict__ Y)
{
  __shared__ _Float16 Ks[2][64][64];     // XOR-swizzled: byte ^= (row&7)<<4
  __shared__ _Float16 Vs[2][64][64];     // [d][i], same swizzle
  __shared__ uint32_t Ps[4][16][32];     // per-wave P, XOR-swizzled dwords
  int bid = blockIdx.x;
  int bh = bid & 63;                     // XCD = bid%8 = bh%8 -> bh-local L2
  int j = bid >> 6;                      // 0..15
  const int jts[2] = { j, 31-j };
  int maxjt = 31 - j;
  int b = bh >> 4, h = bh & 15;
  int tid = threadIdx.x, wave = tid >> 6, lane = tid & 63;
  int g = lane >> 4, l15 = lane & 15;
  uint32_t* Pw = &Ps[wave][0][0] + l15*32;
  int xm = (l15 & 7) << 2;
  int swR = (l15 & 7) << 4;              // read-side swizzle (row = ..l15)
  const _Float16 QS = (_Float16)0.18033688f;   // 0.125 * log2(e)
  const float OFF = 12.0f;               // fixed softmax offset (log2 domain)

  int q0[2];
  f16x8 qf0[2], qf1[2];
  #pragma unroll
  for (int t = 0; t < 2; t++){
    q0[t] = jts[t]*64 + wave*16;
    const _Float16* qp = qkv + (size_t)(b*2048 + q0[t] + l15)*N3C_ + 1024 + h*64;
    qf0[t] = *(const f16x8*)&qp[g*8] * QS;
    qf1[t] = *(const f16x8*)&qp[32 + g*8] * QS;
  }
  float lrun[2] = {0.f, 0.f};
  f32x4 acc[2][4] = {};

  int srow = tid >> 2;                   // staging row 0..63
  int sbyte = (tid & 3)*32;              // staging byte col {0,32,64,96}
  int swW = (srow & 7) << 4;             // write-side swizzle
  const _Float16* kbase = qkv + (size_t)(b*2048 + srow)*N3C_ + h*64 + (sbyte>>1);
  const _Float16* vbase = VTb + ((size_t)bh*64 + srow)*2048 + (sbyte>>1);

  auto stage = [&](int buf, const uint4& k0, const uint4& k1,
                   const uint4& v0, const uint4& v1){
    char* kw = (char*)&Ks[buf][0][0] + srow*128;
    char* vw = (char*)&Vs[buf][0][0] + srow*128;
    *(uint4*)(kw + ( sbyte       ^ swW)) = k0;
    *(uint4*)(kw + ((sbyte + 16) ^ swW)) = k1;
    *(uint4*)(vw + ( sbyte       ^ swW)) = v0;
    *(uint4*)(vw + ((sbyte + 16) ^ swW)) = v1;
  };

  auto process = [&](const f16x8& qa, const f16x8& qb, float& lr,
                     f32x4* ac, int qt0, int i0, bool diag, int cur){
    const char* kb = (const char*)&Ks[cur][0][0];
    const char* vb = (const char*)&Vs[cur][0][0];
    // QK^T (swapped operands); scores in log2 domain via Q pre-scale
    f32x4 s2[4];
    __builtin_amdgcn_s_setprio(1);
    #pragma unroll
    for (int nb = 0; nb < 4; nb++){
      const char* krow = kb + (nb*16 + l15)*128;
      f16x8 kf0 = *(const f16x8*)(krow + (( g*16)      ^ swR));
      f16x8 kf1 = *(const f16x8*)(krow + ((64 + g*16)  ^ swR));
      f32x4 z = {};
      z = __builtin_amdgcn_mfma_f32_16x16x32_f16(kf0, qa, z, 0, 0, 0);
      z = __builtin_amdgcn_mfma_f32_16x16x32_f16(kf1, qb, z, 0, 0, 0);
      s2[nb] = z;
    }
    __builtin_amdgcn_s_setprio(0);
    float p[16];
    #pragma unroll
    for (int nb = 0; nb < 4; nb++)
      #pragma unroll
      for (int r = 0; r < 4; r++)
        p[nb*4 + r] = s2[nb][r];
    if (diag){
      int qidx = qt0 + l15;
      #pragma unroll
      for (int nb = 0; nb < 4; nb++)
        #pragma unroll
        for (int r = 0; r < 4; r++){
          int kidx = i0 + nb*16 + g*4 + r;
          if (kidx > qidx) p[nb*4 + r] = -3e30f;
        }
    }
    // fixed-offset exp2 + pack
    uint32_t pk[8];
    #pragma unroll
    for (int i = 0; i < 8; i++){
      float e0 = __builtin_amdgcn_exp2f(p[2*i]     - OFF);
      float e1 = __builtin_amdgcn_exp2f(p[2*i + 1] - OFF);
      pk[i] = pkrtz(e0, e1);
    }
    // P -> swizzled LDS.  pk[i] with i = nb*2+r2 holds k-pair (nb, g*4+2*r2)
    #pragma unroll
    for (int nb = 0; nb < 4; nb++)
      #pragma unroll
      for (int r2 = 0; r2 < 2; r2++)
        Pw[(nb*8 + g*2 + r2) ^ xm] = pk[nb*2 + r2];
    // PV
    __builtin_amdgcn_s_setprio(1);
    #pragma unroll
    for (int ks = 0; ks < 2; ks++){
      f16x8 pb = *(const f16x8*)&Pw[(ks*16 + g*4) ^ xm];
      #pragma unroll
      for (int db = 0; db < 4; db++){
        const char* vrow = vb + (db*16 + l15)*128;
        f16x8 vv = *(const f16x8*)(vrow + ((ks*64 + g*16) ^ swR));
        ac[db] = __builtin_amdgcn_mfma_f32_16x16x32_f16(vv, pb, ac[db], 0, 0, 0);
      }
    }
    __builtin_amdgcn_s_setprio(0);
    // per-lane partial row-sum (cross-lane reduce deferred to epilogue)
    const h2 ones = { (_Float16)1.0f, (_Float16)1.0f };
    union { uint32_t u; h2 h; } cv;
    float rs0 = 0.f, rs1 = 0.f;
    #pragma unroll
    for (int i = 0; i < 4; i++){
      cv.u = pk[i];     rs0 = __builtin_amdgcn_fdot2(cv.h, ones, rs0, false);
      cv.u = pk[i + 4]; rs1 = __builtin_amdgcn_fdot2(cv.h, ones, rs1, false);
    }
    lr += rs0 + rs1;
  };

  // prologue: load + stage it=0 into buf0
  uint4 ka0 = *(const uint4*)&kbase[0];
  uint4 ka1 = *(const uint4*)&kbase[8];
  uint4 va0 = *(const uint4*)&vbase[0];
  uint4 va1 = *(const uint4*)&vbase[8];
  stage(0, ka0, ka1, va0, va1);
  __syncthreads();
  for (int it = 0; it <= maxjt; ++it){
    int cur = it & 1;
    if (it < maxjt){
      size_t ko = (size_t)(it+1)*64*N3C_;
      int    vo = (it+1)*64;
      ka0 = *(const uint4*)&kbase[ko];
      ka1 = *(const uint4*)&kbase[ko + 8];
      va0 = *(const uint4*)&vbase[vo];
      va1 = *(const uint4*)&vbase[vo + 8];
    }
    process(qf0[1], qf1[1], lrun[1], acc[1], q0[1], it*64, it == jts[1], cur);
    if (it <= jts[0])
      process(qf0[0], qf1[0], lrun[0], acc[0], q0[0], it*64, it == jts[0], cur);
    if (it < maxjt) stage(cur ^ 1, ka0, ka1, va0, va1);
    __syncthreads();
  }

  #pragma unroll
  for (int t = 0; t < 2; t++){
    float rs = lrun[t];
    rs += __shfl_xor(rs, 16);
    rs += __shfl_xor(rs, 32);
    float inv = 1.0f / rs;
    _Float16* yb = Y + (size_t)(b*2048 + q0[t] + l15)*NC_ + h*64 + g*4;
    #pragma unroll
    for (int db = 0; db < 4; db++){
      f16x4 o;
      #pragma unroll
      for (int r = 0; r < 4; r++) o[r] = (_Float16)(acc[t][db][r]*inv);
      *(f16x4*)&yb[db*16] = o;
    }
  }
}

// ---------------------------------------------------------------- launch
extern "C" void kernel_launch(void* const* d_in, const int* in_sizes, int n_in,
                              void* d_out, int out_size, void* d_ws, size_t ws_size,
                              hipStream_t stream)
{
  const float* x      = (const float*)d_in[0];
  const float* w_attn = (const float*)d_in[1];
  const float* b_attn = (const float*)d_in[2];
  const float* w_proj = (const float*)d_in[3];
  const float* b_proj = (const float*)d_in[4];
  float* out = (float*)d_out;
  char* ws = (char*)d_ws;
  _Float16* xb   = (_Float16*)(ws + 0);            // 8192x1024
  _Float16* wT   = (_Float16*)(ws + 16777216);     // 3072x1024
  _Float16* wpT  = (_Float16*)(ws + 23068672);     // 1024x1024
  float*    bp   = (float*)   (ws + 25165824);     // 3072
  _Float16* qkv  = (_Float16*)(ws + 25178112);     // 8192x3072 (parts 0,1 used)
  _Float16* VT   = (_Float16*)(ws + 75509760);     // 64x64x2048
  _Float16* Y    = (_Float16*)(ws + 92286976);     // 8192x1024

  k_prep<<<2572, 256, 0, stream>>>(x, xb, w_attn, wT, w_proj, wpT, b_attn, bp);
  k_gemm<1><<<dim3(24, 64), 256, 0, stream>>>(xb, wT, bp, qkv, VT, NT_, N3C_, NC_);
  k_attn<<<1024, 256, 0, stream>>>(qkv, VT, Y);
  k_gemm<0><<<dim3(8, 64), 256, 0, stream>>>(Y, wpT, b_proj, out, (_Float16*)nullptr, NT_, NC_, NC_);
}

// Round 15
// 190.251 us; speedup vs baseline: 1.0488x; 1.0488x over previous
//
#include <hip/hip_runtime.h>
#include <stdint.h>

// CausalSelfAttention fused pipeline, MI355X gfx950.
// B=4, T=2048, C=1024, NH=16, HS=64.
// v14: r13 baseline restored (reg-staged GEMM, separate prologue kernels,
//      2-tile attn @ 4 blocks/CU).  GEMM gains 2-deep register prefetch
//      (manual x2 unroll, named staging regs, K must be divisible by 64).

typedef __attribute__((ext_vector_type(8))) _Float16 f16x8;
typedef __attribute__((ext_vector_type(4))) _Float16 f16x4;
typedef __attribute__((ext_vector_type(2))) _Float16 h2;
typedef __attribute__((ext_vector_type(2))) __fp16   fp16x2_t;
typedef __attribute__((ext_vector_type(4))) float    f32x4;

#define NT_   8192    // B*T
#define NC_   1024
#define N3C_  3072

__device__ __forceinline__ uint32_t pkrtz(float a, float b){
  union { fp16x2_t h; uint32_t u; } cv;
  cv.h = __builtin_amdgcn_cvt_pkrtz(a, b);
  return cv.u;
}

// ---------------------------------------------------------------- conversions
__global__ void k_cvt(const float* __restrict__ src, _Float16* __restrict__ dst, int n4){
  int idx = blockIdx.x*blockDim.x + threadIdx.x;
  int stride = gridDim.x*blockDim.x;
  for (int i = idx; i < n4; i += stride){
    float4 v = ((const float4*)src)[i];
    f16x4 o;
    o[0] = (_Float16)v.x; o[1] = (_Float16)v.y;
    o[2] = (_Float16)v.z; o[3] = (_Float16)v.w;
    ((f16x4*)dst)[i] = o;
  }
}

// wT'[m'][c] = w_attn[c][colmap(m')],  m' = part*1024 + h*64 + d,
// colmap(m') = part*1024 + d*16 + h.
__global__ void k_wattn_t(const float* __restrict__ w, _Float16* __restrict__ wt){
  int t = threadIdx.x;                 // 128
  int m0 = blockIdx.x*128, c0 = blockIdx.y*32;
  int mcol = m0 + t;
  int part = mcol >> 10, rr = mcol & 1023;
  int mp = part*1024 + (rr & 15)*64 + (rr >> 4);
  alignas(16) _Float16 buf[32];
  #pragma unroll
  for (int cc = 0; cc < 32; cc++)
    buf[cc] = (_Float16)w[(size_t)(c0+cc)*N3C_ + mcol];
  uint4* dst = (uint4*)(wt + (size_t)mp*NC_ + c0);
  const uint4* sb = (const uint4*)buf;
  dst[0]=sb[0]; dst[1]=sb[1]; dst[2]=sb[2]; dst[3]=sb[3];
}

// wpT'[o][c'] = w_proj[(c'&63)*16 + (c'>>6)][o]
__global__ void k_wproj_t(const float* __restrict__ w, _Float16* __restrict__ wt){
  int t = threadIdx.x;                 // 128
  int o0 = blockIdx.x*128, cp0 = blockIdx.y*32;
  int o = o0 + t;
  alignas(16) _Float16 buf[32];
  #pragma unroll
  for (int i = 0; i < 32; i++){
    int cp = cp0 + i;
    int row = (cp & 63)*16 + (cp >> 6);
    buf[i] = (_Float16)w[(size_t)row*NC_ + o];
  }
  uint4* dst = (uint4*)(wt + (size_t)o*NC_ + cp0);
  const uint4* sb = (const uint4*)buf;
  dst[0]=sb[0]; dst[1]=sb[1]; dst[2]=sb[2]; dst[3]=sb[3];
}

__global__ void k_bias(const float* __restrict__ ba, float* __restrict__ bp){
  int i = blockIdx.x*blockDim.x + threadIdx.x;   // 3072
  int part = i >> 10, rr = i & 1023, h = rr >> 6, d = rr & 63;
  bp[i] = ba[part*1024 + d*16 + h];
}

// ---------------------------------------------------------------- GEMM
// C[m][n] = sum_k A[m][k]*BT[n][k] + bias[n].  128x128 tile, BK=32, 4 waves.
// Register-staged with 2-deep prefetch (named regs, manual x2 unroll).
// Requires K % 64 == 0.  OUT_HALF=1: V-part written in VT layout.
template<int OUT_HALF>
__global__ __launch_bounds__(256) void k_gemm(
    const _Float16* __restrict__ A, const _Float16* __restrict__ BT,
    const float* __restrict__ bias, void* __restrict__ outp,
    _Float16* __restrict__ VTout,
    int M, int N, int K)
{
  __shared__ _Float16 As[128][40];
  __shared__ _Float16 Bs[128][40];
  int tid = threadIdx.x;
  int wave = tid >> 6, lane = tid & 63;
  int wr = wave >> 1, wc = wave & 1;
  int g = lane >> 4, l15 = lane & 15;
  f32x4 acc[4][4] = {};
  const _Float16* Ag = A  + (size_t)blockIdx.y*128*K;
  const _Float16* Bg = BT + (size_t)blockIdx.x*128*K;
  int srow = tid >> 1, skoff = (tid & 1)*16;      // 128 rows x 2 halves of 16
  const _Float16* apt = Ag + (size_t)srow*K + skoff;
  const _Float16* bpt = Bg + (size_t)srow*K + skoff;
  // 2-deep prefetch: slot0 = tile kt, slot1 = tile kt+32
  uint4 a00 = *(const uint4*)apt;
  uint4 a01 = *(const uint4*)(apt + 8);
  uint4 b00 = *(const uint4*)bpt;
  uint4 b01 = *(const uint4*)(bpt + 8);
  uint4 a10 = *(const uint4*)(apt + 32);
  uint4 a11 = *(const uint4*)(apt + 40);
  uint4 b10 = *(const uint4*)(bpt + 32);
  uint4 b11 = *(const uint4*)(bpt + 40);

  auto compute = [&](){
    f16x8 af[4], bf[4];
    #pragma unroll
    for (int mi = 0; mi < 4; mi++) af[mi] = *(const f16x8*)&As[wr*64 + mi*16 + l15][g*8];
    #pragma unroll
    for (int ni = 0; ni < 4; ni++) bf[ni] = *(const f16x8*)&Bs[wc*64 + ni*16 + l15][g*8];
    #pragma unroll
    for (int mi = 0; mi < 4; mi++)
      #pragma unroll
      for (int ni = 0; ni < 4; ni++)
        acc[mi][ni] = __builtin_amdgcn_mfma_f32_16x16x32_f16(af[mi], bf[ni], acc[mi][ni], 0, 0, 0);
  };

  for (int kt = 0; kt < K; kt += 64){
    __syncthreads();
    *(uint4*)&As[srow][skoff]     = a00;
    *(uint4*)&As[srow][skoff + 8] = a01;
    *(uint4*)&Bs[srow][skoff]     = b00;
    *(uint4*)&Bs[srow][skoff + 8] = b01;
    __syncthreads();
    if (kt + 64 < K){
      a00 = *(const uint4*)(apt + kt + 64);
      a01 = *(const uint4*)(apt + kt + 72);
      b00 = *(const uint4*)(bpt + kt + 64);
      b01 = *(const uint4*)(bpt + kt + 72);
    }
    compute();
    __syncthreads();
    *(uint4*)&As[srow][skoff]     = a10;
    *(uint4*)&As[srow][skoff + 8] = a11;
    *(uint4*)&Bs[srow][skoff]     = b10;
    *(uint4*)&Bs[srow][skoff + 8] = b11;
    __syncthreads();
    if (kt + 96 < K){
      a10 = *(const uint4*)(apt + kt + 96);
      a11 = *(const uint4*)(apt + kt + 104);
      b10 = *(const uint4*)(bpt + kt + 96);
      b11 = *(const uint4*)(bpt + kt + 104);
    }
    compute();
  }
  int rowBase = blockIdx.y*128 + wr*64;
  int colBase = blockIdx.x*128 + wc*64;
  if (OUT_HALF && colBase >= 2048){
    // V-part: write VT[bh][d][t], bh = b*16+h, from col = 2048 + h*64 + d
    int b = rowBase >> 11;
    int t0 = (rowBase & 2047);
    #pragma unroll
    for (int mi = 0; mi < 4; mi++){
      #pragma unroll
      for (int ni = 0; ni < 4; ni++){
        int col = colBase + ni*16 + l15;
        int cc = col - 2048;
        int h = cc >> 6, d = cc & 63;
        float bv = bias[col];
        _Float16* dst = VTout + (((size_t)(b*16 + h)*64 + d)*2048) + t0 + mi*16 + g*4;
        f16x4 o;
        #pragma unroll
        for (int r = 0; r < 4; r++) o[r] = (_Float16)(acc[mi][ni][r] + bv);
        *(f16x4*)dst = o;
      }
    }
    return;
  }
  #pragma unroll
  for (int mi = 0; mi < 4; mi++){
    #pragma unroll
    for (int ni = 0; ni < 4; ni++){
      int col = colBase + ni*16 + l15;
      float bv = bias[col];
      #pragma unroll
      for (int r = 0; r < 4; r++){
        int row = rowBase + mi*16 + g*4 + r;
        float v = acc[mi][ni][r] + bv;
        if (OUT_HALF) ((_Float16*)outp)[(size_t)row*N + col] = (_Float16)v;
        else          ((float*)outp)[(size_t)row*N + col] = v;
      }
    }
  }
}

// ---------------------------------------------------------------- attention
// 2-tile balanced flash attention, swapped-operand fixed-offset softmax.
// P = exp2(s' - 12); ratio cancels offset.  No cross-lane in the loop.
// Grid: 1D 1024; bh = bid&63 (XCD-local), j = bid>>6 in 0..15;
// q-tiles {j, 31-j}: uniform 33 processes/block, 4 blocks/CU (160KiB LDS).
__global__ __launch_bounds__(256) void k_attn(
    const _Float16* __restrict__ qkv, const _Float16* __restrict__ VTb,
    _Float16* __restrict__ Y)
{
  __shared__ _Float16 Ks[2][64][64];     // XOR-swizzled: byte ^= (row&7)<<4
  __shared__ _Float16 Vs[2][64][64];     // [d][i], same swizzle
  __shared__ uint32_t Ps[4][16][32];     // per-wave P, XOR-swizzled dwords
  int bid = blockIdx.x;
  int bh = bid & 63;                     // XCD = bid%8 = bh%8 -> bh-local L2
  int j = bid >> 6;                      // 0..15
  const int jts[2] = { j, 31-j };
  int maxjt = 31 - j;
  int b = bh >> 4, h = bh & 15;
  int tid = threadIdx.x, wave = tid >> 6, lane = tid & 63;
  int g = lane >> 4, l15 = lane & 15;
  uint32_t* Pw = &Ps[wave][0][0] + l15*32;
  int xm = (l15 & 7) << 2;
  int swR = (l15 & 7) << 4;              // read-side swizzle (row = ..l15)
  const _Float16 QS = (_Float16)0.18033688f;   // 0.125 * log2(e)
  const float OFF = 12.0f;               // fixed softmax offset (log2 domain)

  int q0[2];
  f16x8 qf0[2], qf1[2];
  #pragma unroll
  for (int t = 0; t < 2; t++){
    q0[t] = jts[t]*64 + wave*16;
    const _Float16* qp = qkv + (size_t)(b*2048 + q0[t] + l15)*N3C_ + 1024 + h*64;
    qf0[t] = *(const f16x8*)&qp[g*8] * QS;
    qf1[t] = *(const f16x8*)&qp[32 + g*8] * QS;
  }
  float lrun[2] = {0.f, 0.f};
  f32x4 acc[2][4] = {};

  int srow = tid >> 2;                   // staging row 0..63
  int sbyte = (tid & 3)*32;              // staging byte col {0,32,64,96}
  int swW = (srow & 7) << 4;             // write-side swizzle
  const _Float16* kbase = qkv + (size_t)(b*2048 + srow)*N3C_ + h*64 + (sbyte>>1);
  const _Float16* vbase = VTb + ((size_t)bh*64 + srow)*2048 + (sbyte>>1);

  auto stage = [&](int buf, const uint4& k0, const uint4& k1,
                   const uint4& v0, const uint4& v1){
    char* kw = (char*)&Ks[buf][0][0] + srow*128;
    char* vw = (char*)&Vs[buf][0][0] + srow*128;
    *(uint4*)(kw + ( sbyte       ^ swW)) = k0;
    *(uint4*)(kw + ((sbyte + 16) ^ swW)) = k1;
    *(uint4*)(vw + ( sbyte       ^ swW)) = v0;
    *(uint4*)(vw + ((sbyte + 16) ^ swW)) = v1;
  };

  auto process = [&](const f16x8& qa, const f16x8& qb, float& lr,
                     f32x4* ac, int qt0, int i0, bool diag, int cur){
    const char* kb = (const char*)&Ks[cur][0][0];
    const char* vb = (const char*)&Vs[cur][0][0];
    // QK^T (swapped operands); scores in log2 domain via Q pre-scale
    f32x4 s2[4];
    __builtin_amdgcn_s_setprio(1);
    #pragma unroll
    for (int nb = 0; nb < 4; nb++){
      const char* krow = kb + (nb*16 + l15)*128;
      f16x8 kf0 = *(const f16x8*)(krow + (( g*16)      ^ swR));
      f16x8 kf1 = *(const f16x8*)(krow + ((64 + g*16)  ^ swR));
      f32x4 z = {};
      z = __builtin_amdgcn_mfma_f32_16x16x32_f16(kf0, qa, z, 0, 0, 0);
      z = __builtin_amdgcn_mfma_f32_16x16x32_f16(kf1, qb, z, 0, 0, 0);
      s2[nb] = z;
    }
    __builtin_amdgcn_s_setprio(0);
    float p[16];
    #pragma unroll
    for (int nb = 0; nb < 4; nb++)
      #pragma unroll
      for (int r = 0; r < 4; r++)
        p[nb*4 + r] = s2[nb][r];
    if (diag){
      int qidx = qt0 + l15;
      #pragma unroll
      for (int nb = 0; nb < 4; nb++)
        #pragma unroll
        for (int r = 0; r < 4; r++){
          int kidx = i0 + nb*16 + g*4 + r;
          if (kidx > qidx) p[nb*4 + r] = -3e30f;
        }
    }
    // fixed-offset exp2 + pack
    uint32_t pk[8];
    #pragma unroll
    for (int i = 0; i < 8; i++){
      float e0 = __builtin_amdgcn_exp2f(p[2*i]     - OFF);
      float e1 = __builtin_amdgcn_exp2f(p[2*i + 1] - OFF);
      pk[i] = pkrtz(e0, e1);
    }
    // P -> swizzled LDS.  pk[i] with i = nb*2+r2 holds k-pair (nb, g*4+2*r2)
    #pragma unroll
    for (int nb = 0; nb < 4; nb++)
      #pragma unroll
      for (int r2 = 0; r2 < 2; r2++)
        Pw[(nb*8 + g*2 + r2) ^ xm] = pk[nb*2 + r2];
    // PV
    __builtin_amdgcn_s_setprio(1);
    #pragma unroll
    for (int ks = 0; ks < 2; ks++){
      f16x8 pb = *(const f16x8*)&Pw[(ks*16 + g*4) ^ xm];
      #pragma unroll
      for (int db = 0; db < 4; db++){
        const char* vrow = vb + (db*16 + l15)*128;
        f16x8 vv = *(const f16x8*)(vrow + ((ks*64 + g*16) ^ swR));
        ac[db] = __builtin_amdgcn_mfma_f32_16x16x32_f16(vv, pb, ac[db], 0, 0, 0);
      }
    }
    __builtin_amdgcn_s_setprio(0);
    // per-lane partial row-sum (cross-lane reduce deferred to epilogue)
    const h2 ones = { (_Float16)1.0f, (_Float16)1.0f };
    union { uint32_t u; h2 h; } cv;
    float rs0 = 0.f, rs1 = 0.f;
    #pragma unroll
    for (int i = 0; i < 4; i++){
      cv.u = pk[i];     rs0 = __builtin_amdgcn_fdot2(cv.h, ones, rs0, false);
      cv.u = pk[i + 4]; rs1 = __builtin_amdgcn_fdot2(cv.h, ones, rs1, false);
    }
    lr += rs0 + rs1;
  };

  // prologue: load + stage it=0 into buf0
  uint4 ka0 = *(const uint4*)&kbase[0];
  uint4 ka1 = *(const uint4*)&kbase[8];
  uint4 va0 = *(const uint4*)&vbase[0];
  uint4 va1 = *(const uint4*)&vbase[8];
  stage(0, ka0, ka1, va0, va1);
  __syncthreads();
  for (int it = 0; it <= maxjt; ++it){
    int cur = it & 1;
    if (it < maxjt){
      size_t ko = (size_t)(it+1)*64*N3C_;
      int    vo = (it+1)*64;
      ka0 = *(const uint4*)&kbase[ko];
      ka1 = *(const uint4*)&kbase[ko + 8];
      va0 = *(const uint4*)&vbase[vo];
      va1 = *(const uint4*)&vbase[vo + 8];
    }
    process(qf0[1], qf1[1], lrun[1], acc[1], q0[1], it*64, it == jts[1], cur);
    if (it <= jts[0])
      process(qf0[0], qf1[0], lrun[0], acc[0], q0[0], it*64, it == jts[0], cur);
    if (it < maxjt) stage(cur ^ 1, ka0, ka1, va0, va1);
    __syncthreads();
  }

  #pragma unroll
  for (int t = 0; t < 2; t++){
    float rs = lrun[t];
    rs += __shfl_xor(rs, 16);
    rs += __shfl_xor(rs, 32);
    float inv = 1.0f / rs;
    _Float16* yb = Y + (size_t)(b*2048 + q0[t] + l15)*NC_ + h*64 + g*4;
    #pragma unroll
    for (int db = 0; db < 4; db++){
      f16x4 o;
      #pragma unroll
      for (int r = 0; r < 4; r++) o[r] = (_Float16)(acc[t][db][r]*inv);
      *(f16x4*)&yb[db*16] = o;
    }
  }
}

// ---------------------------------------------------------------- launch
extern "C" void kernel_launch(void* const* d_in, const int* in_sizes, int n_in,
                              void* d_out, int out_size, void* d_ws, size_t ws_size,
                              hipStream_t stream)
{
  const float* x      = (const float*)d_in[0];
  const float* w_attn = (const float*)d_in[1];
  const float* b_attn = (const float*)d_in[2];
  const float* w_proj = (const float*)d_in[3];
  const float* b_proj = (const float*)d_in[4];
  float* out = (float*)d_out;
  char* ws = (char*)d_ws;
  _Float16* xb   = (_Float16*)(ws + 0);            // 8192x1024
  _Float16* wT   = (_Float16*)(ws + 16777216);     // 3072x1024
  _Float16* wpT  = (_Float16*)(ws + 23068672);     // 1024x1024
  float*    bp   = (float*)   (ws + 25165824);     // 3072
  _Float16* qkv  = (_Float16*)(ws + 25178112);     // 8192x3072 (parts 0,1 used)
  _Float16* VT   = (_Float16*)(ws + 75509760);     // 64x64x2048
  _Float16* Y    = (_Float16*)(ws + 92286976);     // 8192x1024

  k_cvt<<<2048, 256, 0, stream>>>(x, xb, (NT_*NC_)/4);
  k_wattn_t<<<dim3(24, 32), 128, 0, stream>>>(w_attn, wT);
  k_wproj_t<<<dim3(8, 32), 128, 0, stream>>>(w_proj, wpT);
  k_bias<<<12, 256, 0, stream>>>(b_attn, bp);
  k_gemm<1><<<dim3(24, 64), 256, 0, stream>>>(xb, wT, bp, qkv, VT, NT_, N3C_, NC_);
  k_attn<<<1024, 256, 0, stream>>>(qkv, VT, Y);
  k_gemm<0><<<dim3(8, 64), 256, 0, stream>>>(Y, wpT, b_proj, out, (_Float16*)nullptr, NT_, NC_, NC_);
}

// Round 16
// 186.022 us; speedup vs baseline: 1.0726x; 1.0227x over previous
//
#include <hip/hip_runtime.h>
#include <stdint.h>

// CausalSelfAttention fused pipeline, MI355X gfx950.
// B=4, T=2048, C=1024, NH=16, HS=64.
// v15: QKV GEMM -> 256x256 8-wave 8-phase schedule (T2 swizzle + T3/T4
//      counted vmcnt + T5 setprio), derived from the m201 template with
//      a fully ledgered stage/overwrite/lead schedule.
//      Proj GEMM, attention, prologue kernels unchanged from r15.

typedef __attribute__((ext_vector_type(8))) _Float16 f16x8;
typedef __attribute__((ext_vector_type(4))) _Float16 f16x4;
typedef __attribute__((ext_vector_type(2))) _Float16 h2;
typedef __attribute__((ext_vector_type(2))) __fp16   fp16x2_t;
typedef __attribute__((ext_vector_type(4))) float    f32x4;

#define NT_   8192    // B*T
#define NC_   1024
#define N3C_  3072

__device__ __forceinline__ uint32_t pkrtz(float a, float b){
  union { fp16x2_t h; uint32_t u; } cv;
  cv.h = __builtin_amdgcn_cvt_pkrtz(a, b);
  return cv.u;
}
__device__ __forceinline__ void glds16(const _Float16* g, _Float16* l){
  __builtin_amdgcn_global_load_lds((const __attribute__((address_space(1))) void*)g,
                                   (__attribute__((address_space(3))) void*)l, 16, 0, 0);
}

#define ASM_VMCNT(N) asm volatile("s_waitcnt vmcnt(" #N ")" ::: "memory")
#define ASM_BAR()    asm volatile("s_barrier" ::: "memory")

// ---------------------------------------------------------------- conversions
__global__ void k_cvt(const float* __restrict__ src, _Float16* __restrict__ dst, int n4){
  int idx = blockIdx.x*blockDim.x + threadIdx.x;
  int stride = gridDim.x*blockDim.x;
  for (int i = idx; i < n4; i += stride){
    float4 v = ((const float4*)src)[i];
    f16x4 o;
    o[0] = (_Float16)v.x; o[1] = (_Float16)v.y;
    o[2] = (_Float16)v.z; o[3] = (_Float16)v.w;
    ((f16x4*)dst)[i] = o;
  }
}

// wT'[m'][c] = w_attn[c][colmap(m')],  m' = part*1024 + h*64 + d,
// colmap(m') = part*1024 + d*16 + h.
__global__ void k_wattn_t(const float* __restrict__ w, _Float16* __restrict__ wt){
  int t = threadIdx.x;                 // 128
  int m0 = blockIdx.x*128, c0 = blockIdx.y*32;
  int mcol = m0 + t;
  int part = mcol >> 10, rr = mcol & 1023;
  int mp = part*1024 + (rr & 15)*64 + (rr >> 4);
  alignas(16) _Float16 buf[32];
  #pragma unroll
  for (int cc = 0; cc < 32; cc++)
    buf[cc] = (_Float16)w[(size_t)(c0+cc)*N3C_ + mcol];
  uint4* dst = (uint4*)(wt + (size_t)mp*NC_ + c0);
  const uint4* sb = (const uint4*)buf;
  dst[0]=sb[0]; dst[1]=sb[1]; dst[2]=sb[2]; dst[3]=sb[3];
}

// wpT'[o][c'] = w_proj[(c'&63)*16 + (c'>>6)][o]
__global__ void k_wproj_t(const float* __restrict__ w, _Float16* __restrict__ wt){
  int t = threadIdx.x;                 // 128
  int o0 = blockIdx.x*128, cp0 = blockIdx.y*32;
  int o = o0 + t;
  alignas(16) _Float16 buf[32];
  #pragma unroll
  for (int i = 0; i < 32; i++){
    int cp = cp0 + i;
    int row = (cp & 63)*16 + (cp >> 6);
    buf[i] = (_Float16)w[(size_t)row*NC_ + o];
  }
  uint4* dst = (uint4*)(wt + (size_t)o*NC_ + cp0);
  const uint4* sb = (const uint4*)buf;
  dst[0]=sb[0]; dst[1]=sb[1]; dst[2]=sb[2]; dst[3]=sb[3];
}

__global__ void k_bias(const float* __restrict__ ba, float* __restrict__ bp){
  int i = blockIdx.x*blockDim.x + threadIdx.x;   // 3072
  int part = i >> 10, rr = i & 1023, h = rr >> 6, d = rr & 63;
  bp[i] = ba[part*1024 + d*16 + h];
}

// ---------------------------------------------------------------- QKV GEMM
// 256x256 tile, BK=64, 512 threads (2Mx4N waves), 8-phase counted-vmcnt
// schedule.  A = xb [8192][1024] f16, B = wT [3072][1024] f16 (row = out col).
// LDS: A dbuf 2x16K halfs + B dbuf 2x16K halfs = 128 KiB, row-XOR swizzled
// (half-col ^= (row&7)<<3), staged via glds with pre-swizzled global source.
// Stage stream (K-tile tau, phases p0..p3):
//   p0: B(tau+1) both halves [4 glds/thr]   p1: Ah1(tau+1) [2]
//   p2: none                                p3: Ah0(tau+2) [2]
// vmcnt at phase ends: 6/8/6/4 (3-phase issue windows; leads >= 4 phases).
__global__ __launch_bounds__(512, 2) void k_gemm256(
    const _Float16* __restrict__ A, const _Float16* __restrict__ BT,
    const float* __restrict__ bias, _Float16* __restrict__ qkvout,
    _Float16* __restrict__ VTout)
{
  const int K = 1024;
  __shared__ _Float16 LS[65536];
  _Float16* As0 = LS;
  _Float16* As1 = LS + 16384;
  _Float16* Bs0 = LS + 32768;
  _Float16* Bs1 = LS + 49152;
  int tid = threadIdx.x;
  int w = tid >> 6, lane = tid & 63;
  int wm = w >> 2, wn = w & 3;
  int g = lane >> 4, l15 = lane & 15;
  size_t m0 = (size_t)blockIdx.y * 256;
  size_t n0 = (size_t)blockIdx.x * 256;
  f32x4 acc[8][4] = {};

  // staging geometry: per issue, wave w covers rows base + w*8 + (lane>>3),
  // lane chunk (lane&7)*16B; source col pre-swizzled so LDS stays linear.
  int srow8 = w*8 + (lane >> 3);
  int scol  = (((lane & 7) ^ ((lane >> 3) & 7)) << 3);   // halfs
  int sdst  = srow8*64 + (lane & 7)*8;                   // halfs

  auto stageA = [&](int tau, int mh){
    _Float16* dst = (tau & 1) ? As1 : As0;
    const _Float16* src = A + m0*K + tau*64 + scol;
    #pragma unroll
    for (int i = 0; i < 2; i++){
      int base = i*128 + mh*64;
      glds16(src + (size_t)(base + srow8)*K, dst + base*64 + sdst);
    }
  };
  auto stageB = [&](int tau, int h){
    _Float16* dst = (tau & 1) ? Bs1 : Bs0;
    const _Float16* src = BT + n0*K + tau*64 + scol;
    #pragma unroll
    for (int i = 0; i < 2; i++){
      int base = h*128 + i*64;
      glds16(src + (size_t)(base + srow8)*K, dst + base*64 + sdst);
    }
  };

  const int rcol0 = (g*8) ^ ((l15 & 7) << 3);
  const int rcol1 = (32 + g*8) ^ ((l15 & 7) << 3);
  auto readA = [&](int cur, int mh, int kk, f16x8* af){
    const _Float16* Ap = (cur ? As1 : As0) + (wm*128 + mh*64 + l15)*64
                         + (kk ? rcol1 : rcol0);
    #pragma unroll
    for (int mi = 0; mi < 4; mi++)
      af[mi] = *(const f16x8*)(Ap + mi*1024);
  };
  auto readB = [&](int cur, int kk, f16x8* bf){
    const _Float16* Bp = (cur ? Bs1 : Bs0) + (wn*64 + l15)*64
                         + (kk ? rcol1 : rcol0);
    #pragma unroll
    for (int ni = 0; ni < 4; ni++)
      bf[ni] = *(const f16x8*)(Bp + ni*1024);
  };

#define MFMA16(MH, AF, BF) do {                                               \
    __builtin_amdgcn_s_setprio(1);                                            \
    _Pragma("unroll")                                                         \
    for (int mi = 0; mi < 4; mi++)                                            \
      _Pragma("unroll")                                                       \
      for (int ni = 0; ni < 4; ni++)                                          \
        acc[(MH)*4 + mi][ni] = __builtin_amdgcn_mfma_f32_16x16x32_f16(        \
            (AF)[mi], (BF)[ni], acc[(MH)*4 + mi][ni], 0, 0, 0);               \
    __builtin_amdgcn_s_setprio(0);                                            \
  } while (0)

  // prologue: A(0) both halves, B(0) both halves, Ah0(1)  (10 loads)
  stageA(0, 0); stageA(0, 1); stageB(0, 0); stageB(0, 1); stageA(1, 0);
  ASM_VMCNT(2);          // K-tile 0 fully landed (newest 2 = Ah0(1))
  ASM_BAR();

  for (int tau = 0; tau < 16; ++tau){
    int cur = tau & 1;
    f16x8 af[4], bf[4];
    // ---- p0: (kk0, mh0); stage B(tau+1) both halves
    readA(cur, 0, 0, af); readB(cur, 0, bf);
    stageB(tau + 1, 0); stageB(tau + 1, 1);
    ASM_BAR();
    MFMA16(0, af, bf);
    ASM_VMCNT(6); ASM_BAR();
    // ---- p1: (kk0, mh1); stage Ah1(tau+1)
    readA(cur, 1, 0, af);
    stageA(tau + 1, 1);
    ASM_BAR();
    MFMA16(1, af, bf);
    ASM_VMCNT(8); ASM_BAR();
    // ---- p2: (kk1, mh0); no stage
    readA(cur, 0, 1, af); readB(cur, 1, bf);
    ASM_BAR();
    MFMA16(0, af, bf);
    ASM_VMCNT(6); ASM_BAR();
    // ---- p3: (kk1, mh1); stage Ah0(tau+2)
    readA(cur, 1, 1, af);
    stageA(tau + 2, 0);
    ASM_BAR();
    MFMA16(1, af, bf);
    ASM_VMCNT(4); ASM_BAR();
  }
#undef MFMA16

  // epilogue
  int rowBase = (int)m0 + wm*128;
  int colBase = (int)n0 + wn*64;
  if (colBase >= 2048){
    // V-part: VT[bh][d][t] from col = 2048 + h*64 + d
    int b = rowBase >> 11;
    int t0 = rowBase & 2047;
    #pragma unroll
    for (int mi = 0; mi < 8; mi++){
      #pragma unroll
      for (int ni = 0; ni < 4; ni++){
        int col = colBase + ni*16 + l15;
        int cc = col - 2048;
        int h = cc >> 6, d = cc & 63;
        float bv = bias[col];
        _Float16* dst = VTout + (((size_t)(b*16 + h)*64 + d)*2048)
                        + t0 + mi*16 + g*4;
        f16x4 o;
        #pragma unroll
        for (int r = 0; r < 4; r++) o[r] = (_Float16)(acc[mi][ni][r] + bv);
        *(f16x4*)dst = o;
      }
    }
    return;
  }
  #pragma unroll
  for (int mi = 0; mi < 8; mi++){
    #pragma unroll
    for (int ni = 0; ni < 4; ni++){
      int col = colBase + ni*16 + l15;
      float bv = bias[col];
      #pragma unroll
      for (int r = 0; r < 4; r++){
        int row = rowBase + mi*16 + g*4 + r;
        qkvout[(size_t)row*N3C_ + col] = (_Float16)(acc[mi][ni][r] + bv);
      }
    }
  }
}

// ---------------------------------------------------------------- proj GEMM
// 128x128 tile, BK=32, 4 waves, register-staged (proven).  f32 output.
__global__ __launch_bounds__(256) void k_gemm_proj(
    const _Float16* __restrict__ A, const _Float16* __restrict__ BT,
    const float* __restrict__ bias, float* __restrict__ outp,
    int M, int N, int K)
{
  __shared__ _Float16 As[128][40];
  __shared__ _Float16 Bs[128][40];
  int tid = threadIdx.x;
  int wave = tid >> 6, lane = tid & 63;
  int wr = wave >> 1, wc = wave & 1;
  int g = lane >> 4, l15 = lane & 15;
  f32x4 acc[4][4] = {};
  const _Float16* Ag = A  + (size_t)blockIdx.y*128*K;
  const _Float16* Bg = BT + (size_t)blockIdx.x*128*K;
  int srow = tid >> 1, skoff = (tid & 1)*16;
  const _Float16* apt = Ag + (size_t)srow*K + skoff;
  const _Float16* bpt = Bg + (size_t)srow*K + skoff;
  uint4 ra0 = *(const uint4*)apt;
  uint4 ra1 = *(const uint4*)(apt + 8);
  uint4 rb0 = *(const uint4*)bpt;
  uint4 rb1 = *(const uint4*)(bpt + 8);
  for (int kt = 0; kt < K; kt += 32){
    __syncthreads();
    *(uint4*)&As[srow][skoff]     = ra0;
    *(uint4*)&As[srow][skoff + 8] = ra1;
    *(uint4*)&Bs[srow][skoff]     = rb0;
    *(uint4*)&Bs[srow][skoff + 8] = rb1;
    __syncthreads();
    if (kt + 32 < K){
      ra0 = *(const uint4*)(apt + kt + 32);
      ra1 = *(const uint4*)(apt + kt + 40);
      rb0 = *(const uint4*)(bpt + kt + 32);
      rb1 = *(const uint4*)(bpt + kt + 40);
    }
    f16x8 af[4], bf[4];
    #pragma unroll
    for (int mi = 0; mi < 4; mi++) af[mi] = *(const f16x8*)&As[wr*64 + mi*16 + l15][g*8];
    #pragma unroll
    for (int ni = 0; ni < 4; ni++) bf[ni] = *(const f16x8*)&Bs[wc*64 + ni*16 + l15][g*8];
    #pragma unroll
    for (int mi = 0; mi < 4; mi++)
      #pragma unroll
      for (int ni = 0; ni < 4; ni++)
        acc[mi][ni] = __builtin_amdgcn_mfma_f32_16x16x32_f16(af[mi], bf[ni], acc[mi][ni], 0, 0, 0);
  }
  int rowBase = blockIdx.y*128 + wr*64;
  int colBase = blockIdx.x*128 + wc*64;
  #pragma unroll
  for (int mi = 0; mi < 4; mi++){
    #pragma unroll
    for (int ni = 0; ni < 4; ni++){
      int col = colBase + ni*16 + l15;
      float bv = bias[col];
      #pragma unroll
      for (int r = 0; r < 4; r++){
        int row = rowBase + mi*16 + g*4 + r;
        outp[(size_t)row*N + col] = acc[mi][ni][r] + bv;
      }
    }
  }
}

// ---------------------------------------------------------------- attention
// 2-tile balanced flash attention, swapped-operand fixed-offset softmax.
// P = exp2(s' - 12); ratio cancels offset.  No cross-lane in the loop.
// Grid: 1D 1024; bh = bid&63 (XCD-local), j = bid>>6 in 0..15;
// q-tiles {j, 31-j}: uniform 33 processes/block, 4 blocks/CU (160KiB LDS).
__global__ __launch_bounds__(256) void k_attn(
    const _Float16* __restrict__ qkv, const _Float16* __restrict__ VTb,
    _Float16* __restrict__ Y)
{
  __shared__ _Float16 Ks[2][64][64];     // XOR-swizzled: byte ^= (row&7)<<4
  __shared__ _Float16 Vs[2][64][64];     // [d][i], same swizzle
  __shared__ uint32_t Ps[4][16][32];     // per-wave P, XOR-swizzled dwords
  int bid = blockIdx.x;
  int bh = bid & 63;                     // XCD = bid%8 = bh%8 -> bh-local L2
  int j = bid >> 6;                      // 0..15
  const int jts[2] = { j, 31-j };
  int maxjt = 31 - j;
  int b = bh >> 4, h = bh & 15;
  int tid = threadIdx.x, wave = tid >> 6, lane = tid & 63;
  int g = lane >> 4, l15 = lane & 15;
  uint32_t* Pw = &Ps[wave][0][0] + l15*32;
  int xm = (l15 & 7) << 2;
  int swR = (l15 & 7) << 4;              // read-side swizzle (row = ..l15)
  const _Float16 QS = (_Float16)0.18033688f;   // 0.125 * log2(e)
  const float OFF = 12.0f;               // fixed softmax offset (log2 domain)

  int q0[2];
  f16x8 qf0[2], qf1[2];
  #pragma unroll
  for (int t = 0; t < 2; t++){
    q0[t] = jts[t]*64 + wave*16;
    const _Float16* qp = qkv + (size_t)(b*2048 + q0[t] + l15)*N3C_ + 1024 + h*64;
    qf0[t] = *(const f16x8*)&qp[g*8] * QS;
    qf1[t] = *(const f16x8*)&qp[32 + g*8] * QS;
  }
  float lrun[2] = {0.f, 0.f};
  f32x4 acc[2][4] = {};

  int srow = tid >> 2;                   // staging row 0..63
  int sbyte = (tid & 3)*32;              // staging byte col {0,32,64,96}
  int swW = (srow & 7) << 4;             // write-side swizzle
  const _Float16* kbase = qkv + (size_t)(b*2048 + srow)*N3C_ + h*64 + (sbyte>>1);
  const _Float16* vbase = VTb + ((size_t)bh*64 + srow)*2048 + (sbyte>>1);

  auto stage = [&](int buf, const uint4& k0, const uint4& k1,
                   const uint4& v0, const uint4& v1){
    char* kw = (char*)&Ks[buf][0][0] + srow*128;
    char* vw = (char*)&Vs[buf][0][0] + srow*128;
    *(uint4*)(kw + ( sbyte       ^ swW)) = k0;
    *(uint4*)(kw + ((sbyte + 16) ^ swW)) = k1;
    *(uint4*)(vw + ( sbyte       ^ swW)) = v0;
    *(uint4*)(vw + ((sbyte + 16) ^ swW)) = v1;
  };

  auto process = [&](const f16x8& qa, const f16x8& qb, float& lr,
                     f32x4* ac, int qt0, int i0, bool diag, int cur){
    const char* kb = (const char*)&Ks[cur][0][0];
    const char* vb = (const char*)&Vs[cur][0][0];
    // QK^T (swapped operands); scores in log2 domain via Q pre-scale
    f32x4 s2[4];
    __builtin_amdgcn_s_setprio(1);
    #pragma unroll
    for (int nb = 0; nb < 4; nb++){
      const char* krow = kb + (nb*16 + l15)*128;
      f16x8 kf0 = *(const f16x8*)(krow + (( g*16)      ^ swR));
      f16x8 kf1 = *(const f16x8*)(krow + ((64 + g*16)  ^ swR));
      f32x4 z = {};
      z = __builtin_amdgcn_mfma_f32_16x16x32_f16(kf0, qa, z, 0, 0, 0);
      z = __builtin_amdgcn_mfma_f32_16x16x32_f16(kf1, qb, z, 0, 0, 0);
      s2[nb] = z;
    }
    __builtin_amdgcn_s_setprio(0);
    float p[16];
    #pragma unroll
    for (int nb = 0; nb < 4; nb++)
      #pragma unroll
      for (int r = 0; r < 4; r++)
        p[nb*4 + r] = s2[nb][r];
    if (diag){
      int qidx = qt0 + l15;
      #pragma unroll
      for (int nb = 0; nb < 4; nb++)
        #pragma unroll
        for (int r = 0; r < 4; r++){
          int kidx = i0 + nb*16 + g*4 + r;
          if (kidx > qidx) p[nb*4 + r] = -3e30f;
        }
    }
    // fixed-offset exp2 + pack
    uint32_t pk[8];
    #pragma unroll
    for (int i = 0; i < 8; i++){
      float e0 = __builtin_amdgcn_exp2f(p[2*i]     - OFF);
      float e1 = __builtin_amdgcn_exp2f(p[2*i + 1] - OFF);
      pk[i] = pkrtz(e0, e1);
    }
    // P -> swizzled LDS.  pk[i] with i = nb*2+r2 holds k-pair (nb, g*4+2*r2)
    #pragma unroll
    for (int nb = 0; nb < 4; nb++)
      #pragma unroll
      for (int r2 = 0; r2 < 2; r2++)
        Pw[(nb*8 + g*2 + r2) ^ xm] = pk[nb*2 + r2];
    // PV
    __builtin_amdgcn_s_setprio(1);
    #pragma unroll
    for (int ks = 0; ks < 2; ks++){
      f16x8 pb = *(const f16x8*)&Pw[(ks*16 + g*4) ^ xm];
      #pragma unroll
      for (int db = 0; db < 4; db++){
        const char* vrow = vb + (db*16 + l15)*128;
        f16x8 vv = *(const f16x8*)(vrow + ((ks*64 + g*16) ^ swR));
        ac[db] = __builtin_amdgcn_mfma_f32_16x16x32_f16(vv, pb, ac[db], 0, 0, 0);
      }
    }
    __builtin_amdgcn_s_setprio(0);
    // per-lane partial row-sum (cross-lane reduce deferred to epilogue)
    const h2 ones = { (_Float16)1.0f, (_Float16)1.0f };
    union { uint32_t u; h2 h; } cv;
    float rs0 = 0.f, rs1 = 0.f;
    #pragma unroll
    for (int i = 0; i < 4; i++){
      cv.u = pk[i];     rs0 = __builtin_amdgcn_fdot2(cv.h, ones, rs0, false);
      cv.u = pk[i + 4]; rs1 = __builtin_amdgcn_fdot2(cv.h, ones, rs1, false);
    }
    lr += rs0 + rs1;
  };

  // prologue: load + stage it=0 into buf0
  uint4 ka0 = *(const uint4*)&kbase[0];
  uint4 ka1 = *(const uint4*)&kbase[8];
  uint4 va0 = *(const uint4*)&vbase[0];
  uint4 va1 = *(const uint4*)&vbase[8];
  stage(0, ka0, ka1, va0, va1);
  __syncthreads();
  for (int it = 0; it <= maxjt; ++it){
    int cur = it & 1;
    if (it < maxjt){
      size_t ko = (size_t)(it+1)*64*N3C_;
      int    vo = (it+1)*64;
      ka0 = *(const uint4*)&kbase[ko];
      ka1 = *(const uint4*)&kbase[ko + 8];
      va0 = *(const uint4*)&vbase[vo];
      va1 = *(const uint4*)&vbase[vo + 8];
    }
    process(qf0[1], qf1[1], lrun[1], acc[1], q0[1], it*64, it == jts[1], cur);
    if (it <= jts[0])
      process(qf0[0], qf1[0], lrun[0], acc[0], q0[0], it*64, it == jts[0], cur);
    if (it < maxjt) stage(cur ^ 1, ka0, ka1, va0, va1);
    __syncthreads();
  }

  #pragma unroll
  for (int t = 0; t < 2; t++){
    float rs = lrun[t];
    rs += __shfl_xor(rs, 16);
    rs += __shfl_xor(rs, 32);
    float inv = 1.0f / rs;
    _Float16* yb = Y + (size_t)(b*2048 + q0[t] + l15)*NC_ + h*64 + g*4;
    #pragma unroll
    for (int db = 0; db < 4; db++){
      f16x4 o;
      #pragma unroll
      for (int r = 0; r < 4; r++) o[r] = (_Float16)(acc[t][db][r]*inv);
      *(f16x4*)&yb[db*16] = o;
    }
  }
}

// ---------------------------------------------------------------- launch
extern "C" void kernel_launch(void* const* d_in, const int* in_sizes, int n_in,
                              void* d_out, int out_size, void* d_ws, size_t ws_size,
                              hipStream_t stream)
{
  const float* x      = (const float*)d_in[0];
  const float* w_attn = (const float*)d_in[1];
  const float* b_attn = (const float*)d_in[2];
  const float* w_proj = (const float*)d_in[3];
  const float* b_proj = (const float*)d_in[4];
  float* out = (float*)d_out;
  char* ws = (char*)d_ws;
  _Float16* xb   = (_Float16*)(ws + 0);            // 8192x1024
  _Float16* wT   = (_Float16*)(ws + 16777216);     // 3072x1024
  _Float16* wpT  = (_Float16*)(ws + 23068672);     // 1024x1024
  float*    bp   = (float*)   (ws + 25165824);     // 3072
  _Float16* qkv  = (_Float16*)(ws + 25178112);     // 8192x3072 (parts 0,1 used)
  _Float16* VT   = (_Float16*)(ws + 75509760);     // 64x64x2048
  _Float16* Y    = (_Float16*)(ws + 92286976);     // 8192x1024

  k_cvt<<<2048, 256, 0, stream>>>(x, xb, (NT_*NC_)/4);
  k_wattn_t<<<dim3(24, 32), 128, 0, stream>>>(w_attn, wT);
  k_wproj_t<<<dim3(8, 32), 128, 0, stream>>>(w_proj, wpT);
  k_bias<<<12, 256, 0, stream>>>(b_attn, bp);
  k_gemm256<<<dim3(12, 32), 512, 0, stream>>>(xb, wT, bp, qkv, VT);
  k_attn<<<1024, 256, 0, stream>>>(qkv, VT, Y);
  k_gemm_proj<<<dim3(8, 64), 256, 0, stream>>>(Y, wpT, b_proj, out, NT_, NC_, NC_);
}